// Round 3
// baseline (220.839 us; speedup 1.0000x reference)
//
#include <hip/hip_runtime.h>
#include <hip/hip_bf16.h>

// GeometricAttention on MI355X (gfx950).
// B=2, T=2048, C=1024, H=16, hd=64, QK-dim=3.
// HARNESS DTYPES: reference is pure float32 -> d_in are float*, d_out is float*.
// Internally we cast to bf16 for MFMA (fp32 accumulate); scores in fp32.
// Pipeline:
//   k_cast         : x (fp32) -> xb (bf16), vectorized
//   k_transpose x4 : wq,wk -> wqkT (96x1024 bf16), wv -> wvT, wo -> woT (cast+transpose)
//   k_qkproj       : MFMA 16-row tiles, xb @ [wq|wk]; folds q~ = (scale*I + d d^T) q
//                    writes Qt,Kt as fp32 planes [bh][c][t]
//   k_gemm_bt      : 128x128x32 MFMA GEMM (m97 structure, global_load_lds w=16)
//                    mode 0: VT[bh][d][t] = wvT @ xb^T (bf16 out, coalesced)
//                    mode 1: out = att @ wo (fp32 out)
//   k_attn         : flash-style, no online max (scores bounded << fp32 exp range,
//                    clamped at 80 as insurance), row sums via ones-row MFMA n-tile.

typedef short bf16x8 __attribute__((ext_vector_type(8)));
typedef float f32x4 __attribute__((ext_vector_type(4)));
typedef __hip_bfloat16 bf16_t;
typedef unsigned int __attribute__((address_space(1))) u32_as1;
typedef unsigned int __attribute__((address_space(3))) u32_as3;

#define T_SEQ 2048
#define NHEAD 16
#define CDIM 1024

__device__ __forceinline__ void gl_lds16(const void* g, void* l) {
  __builtin_amdgcn_global_load_lds((const u32_as1*)g, (u32_as3*)l, 16, 0, 0);
}

__device__ __forceinline__ f32x4 mfma16(bf16x8 a, bf16x8 b, f32x4 c) {
  return __builtin_amdgcn_mfma_f32_16x16x32_bf16(a, b, c, 0, 0, 0);
}

__device__ __forceinline__ unsigned short f2bf(float f) {
  __hip_bfloat16 h = __float2bfloat16(f);
  return *(unsigned short*)&h;
}

// ---------------- cast fp32 -> bf16, 4 elems/thread ----------------
__global__ __launch_bounds__(256) void k_cast(const float4* __restrict__ src,
                                              ushort4* __restrict__ dst, int n4) {
  int i = blockIdx.x * 256 + threadIdx.x;
  if (i < n4) {
    float4 v = src[i];
    ushort4 o;
    o.x = f2bf(v.x); o.y = f2bf(v.y); o.z = f2bf(v.z); o.w = f2bf(v.w);
    dst[i] = o;
  }
}

// ---------------- transpose+cast (fp32 R x C -> bf16 C x R) ----------------
__global__ __launch_bounds__(256) void k_transpose(const float* __restrict__ src,
                                                   bf16_t* __restrict__ dst,
                                                   int R, int C) {
  __shared__ bf16_t tile[32][33];
  int tid = threadIdx.x, tx = tid & 31, ty = tid >> 5;
  int r0 = blockIdx.y * 32, c0 = blockIdx.x * 32;
#pragma unroll
  for (int j = 0; j < 32; j += 8) {
    int r = r0 + ty + j, c = c0 + tx;
    if (r < R && c < C) tile[ty + j][tx] = __float2bfloat16(src[(size_t)r * C + c]);
  }
  __syncthreads();
#pragma unroll
  for (int j = 0; j < 32; j += 8) {
    int c = c0 + ty + j, r = r0 + tx;
    if (r < R && c < C) dst[(size_t)c * R + r] = tile[tx][ty + j];
  }
}

// ---------------- QK projection (M=4096, N=96, K=1024) ----------------
__global__ __launch_bounds__(64) void k_qkproj(const bf16_t* __restrict__ xb,
                                               const bf16_t* __restrict__ wqkT,
                                               const float* __restrict__ head_dirs,
                                               const float* __restrict__ scale,
                                               float* __restrict__ Qt,
                                               float* __restrict__ Kt) {
  __shared__ float q_raw[16][48];
  int lane = threadIdx.x, g = lane >> 4, li = lane & 15;
  int m0 = blockIdx.x * 16;
  f32x4 acc[6] = {};
  for (int k0 = 0; k0 < 1024; k0 += 32) {
    bf16x8 a = *(const bf16x8*)(xb + (size_t)(m0 + li) * 1024 + k0 + g * 8);
#pragma unroll
    for (int nt = 0; nt < 6; ++nt) {
      bf16x8 bb = *(const bf16x8*)(wqkT + (size_t)(nt * 16 + li) * 1024 + k0 + g * 8);
      acc[nt] = mfma16(a, bb, acc[nt]);
    }
  }
  // K part (cols 48..95): store raw k3 into planes [bh][c][t]
#pragma unroll
  for (int nt = 3; nt < 6; ++nt) {
    int n = nt * 16 + li - 48;  // 0..47
    int h = n / 3, c = n - h * 3;
#pragma unroll
    for (int r = 0; r < 4; ++r) {
      int mg = m0 + g * 4 + r;
      int bb = mg >> 11, tt = mg & 2047;
      Kt[(((size_t)bb * NHEAD + h) * 3 + c) * T_SEQ + tt] = acc[nt][r];
    }
  }
  // Q part: needs the 3 comps of one head together -> via LDS, apply M_h
#pragma unroll
  for (int nt = 0; nt < 3; ++nt)
#pragma unroll
    for (int r = 0; r < 4; ++r) q_raw[g * 4 + r][nt * 16 + li] = acc[nt][r];
  __syncthreads();
  float sc = scale[0];
#pragma unroll
  for (int it = 0; it < 4; ++it) {
    int idx = it * 64 + lane;   // row*16 + h
    int row = idx >> 4, h = idx & 15;
    float q0 = q_raw[row][h * 3 + 0];
    float q1 = q_raw[row][h * 3 + 1];
    float q2 = q_raw[row][h * 3 + 2];
    float d0 = head_dirs[h * 3 + 0];
    float d1 = head_dirs[h * 3 + 1];
    float d2 = head_dirs[h * 3 + 2];
    float dot = q0 * d0 + q1 * d1 + q2 * d2;
    int mg = m0 + row;
    int bb = mg >> 11, tt = mg & 2047;
    size_t base = ((size_t)bb * NHEAD + h) * 3 * T_SEQ + tt;
    Qt[base] = sc * q0 + d0 * dot;
    Qt[base + T_SEQ] = sc * q1 + d1 * dot;
    Qt[base + 2 * T_SEQ] = sc * q2 + d2 * dot;
  }
}

// ---------------- 128x128x32 MFMA GEMM, B^T input (m97 structure) ----------------
// C[m][n] = sum_k A[m][k] * Bt[n][k]
// mode 0: bf16 out, VT planes: n=(b,t), store at [(b*1024+m)*2048 + t]
// mode 1: fp32 out, row-major m*N+n
__global__ __launch_bounds__(256) void k_gemm_bt(const bf16_t* __restrict__ A,
                                                 const bf16_t* __restrict__ Bt,
                                                 void* __restrict__ Cout,
                                                 int M, int N, int K, int mode) {
  __shared__ alignas(16) bf16_t As[128 * 32];
  __shared__ alignas(16) bf16_t Bs[128 * 32];
  int tid = threadIdx.x, wave = tid >> 6, lane = tid & 63;
  int g = lane >> 4, li = lane & 15;
  int n0 = blockIdx.x * 128, m0 = blockIdx.y * 128;
  int wm = wave >> 1, wn = wave & 1;

  int c0 = tid, c1 = 256 + tid;  // 16B chunks (512 per 8KB tile)
  const bf16_t* gA0 = A + (size_t)(m0 + (c0 >> 2)) * K + (c0 & 3) * 8;
  const bf16_t* gA1 = A + (size_t)(m0 + (c1 >> 2)) * K + (c1 & 3) * 8;
  const bf16_t* gB0 = Bt + (size_t)(n0 + (c0 >> 2)) * K + (c0 & 3) * 8;
  const bf16_t* gB1 = Bt + (size_t)(n0 + (c1 >> 2)) * K + (c1 & 3) * 8;
  char* lA0 = (char*)As + (size_t)(wave * 64) * 16;
  char* lA1 = (char*)As + (size_t)(256 + wave * 64) * 16;
  char* lB0 = (char*)Bs + (size_t)(wave * 64) * 16;
  char* lB1 = (char*)Bs + (size_t)(256 + wave * 64) * 16;

  f32x4 acc[4][4] = {};

  for (int k0 = 0; k0 < K; k0 += 32) {
    __syncthreads();  // LDS free from previous compute
    gl_lds16(gA0 + k0, lA0);
    gl_lds16(gA1 + k0, lA1);
    gl_lds16(gB0 + k0, lB0);
    gl_lds16(gB1 + k0, lB1);
    __syncthreads();  // vmcnt(0) drain + barrier
    bf16x8 af[4], bfr[4];
#pragma unroll
    for (int mt = 0; mt < 4; ++mt)
      af[mt] = *(const bf16x8*)&As[(wm * 64 + mt * 16 + li) * 32 + g * 8];
#pragma unroll
    for (int nt = 0; nt < 4; ++nt)
      bfr[nt] = *(const bf16x8*)&Bs[(wn * 64 + nt * 16 + li) * 32 + g * 8];
#pragma unroll
    for (int mt = 0; mt < 4; ++mt)
#pragma unroll
      for (int nt = 0; nt < 4; ++nt)
        acc[mt][nt] = mfma16(af[mt], bfr[nt], acc[mt][nt]);
  }

#pragma unroll
  for (int mt = 0; mt < 4; ++mt)
#pragma unroll
    for (int nt = 0; nt < 4; ++nt)
#pragma unroll
      for (int r = 0; r < 4; ++r) {
        int m = m0 + wm * 64 + mt * 16 + g * 4 + r;
        int n = n0 + wn * 64 + nt * 16 + li;
        float v = acc[mt][nt][r];
        if (mode == 0) {
          int bb = n >> 11, tt = n & 2047;
          ((bf16_t*)Cout)[((size_t)bb * 1024 + m) * T_SEQ + tt] = __float2bfloat16(v);
        } else {
          ((float*)Cout)[(size_t)m * N + n] = v;
        }
      }
}

// ---------------- attention ----------------
// block = 256 thr (4 waves), one (b,h) x 64-query tile; wave = 16 queries.
// scores clamped at 80 (exact for sane data); row sums via ones-row MFMA n-tile 4.
__global__ __launch_bounds__(256) void k_attn(const float* __restrict__ Qt,
                                              const float* __restrict__ Kt,
                                              const bf16_t* __restrict__ VT,
                                              bf16_t* __restrict__ att) {
  __shared__ float q_lds[3 * 64];
  __shared__ alignas(16) bf16_t Vt_lds[80][72];      // rows 0..63 = V^T, 64 = ones
  __shared__ alignas(16) bf16_t P_lds[4][16][72];    // per-wave P (16q x 64s), pad 72

  int tid = threadIdx.x, wave = tid >> 6, lane = tid & 63;
  int g = lane >> 4, li = lane & 15;
  int bid = blockIdx.x;
  int qt = (T_SEQ / 64 - 1) - (bid >> 5);  // big-work blocks first
  int bh = bid & 31;
  int b = bh >> 4, h = bh & 15;

  for (int i = tid; i < 16 * 72; i += 256) {  // ones/zeros rows 64..79 (static)
    int rr = i / 72, cc = i % 72;
    Vt_lds[64 + rr][cc] = __float2bfloat16((rr == 0 && cc < 64) ? 1.0f : 0.0f);
  }
  for (int i = tid; i < 4 * 16 * 72; i += 256)  // zero-init P (incl. pad cols)
    ((bf16_t*)P_lds)[i] = __float2bfloat16(0.0f);
  if (tid < 192) {  // q~ tile: 3 comps x 64 queries
    int c = tid >> 6, tq = tid & 63;
    q_lds[c * 64 + tq] = Qt[((size_t)bh * 3 + c) * T_SEQ + qt * 64 + tq];
  }

  const float* Kp = Kt + (size_t)bh * 3 * T_SEQ;
  const bf16_t* Vp = VT + (size_t)bh * 64 * T_SEQ;

  f32x4 acc[5] = {};
  int mw = wave * 16;

  for (int st = 0; st <= qt; ++st) {
    int s0 = st * 64;
    __syncthreads();
#pragma unroll
    for (int p = 0; p < 2; ++p) {  // stage V^T tile 64x64 (padded stride 72)
      int idx = p * 256 + tid;
      int d = idx >> 3, sc8 = (idx & 7) * 8;
      *(uint4*)&Vt_lds[d][sc8] = *(const uint4*)(Vp + (size_t)d * T_SEQ + s0 + sc8);
    }
    __syncthreads();

    float k0v = Kp[s0 + lane];
    float k1v = Kp[T_SEQ + s0 + lane];
    float k2v = Kp[2 * T_SEQ + s0 + lane];
    bool diag = (st == qt);
#pragma unroll
    for (int m = 0; m < 16; ++m) {  // lane = s; 3-FMA score + exp
      float scv = q_lds[mw + m] * k0v + q_lds[64 + mw + m] * k1v +
                  q_lds[128 + mw + m] * k2v;
      scv = fminf(scv, 80.0f);      // insurance: exp can never inf
      float pv = __expf(scv);
      if (diag && lane > mw + m) pv = 0.0f;  // causal (s<=t kept)
      P_lds[wave][m][lane] = __float2bfloat16(pv);
    }
    __syncthreads();  // make P writes unambiguously visible before frag reads

    bf16x8 a0 = *(const bf16x8*)&P_lds[wave][li][g * 8];
    bf16x8 a1 = *(const bf16x8*)&P_lds[wave][li][32 + g * 8];
#pragma unroll
    for (int nt = 0; nt < 5; ++nt) {  // nt 0..3 = O dims, nt 4 = row sums
      bf16x8 b0 = *(const bf16x8*)&Vt_lds[nt * 16 + li][g * 8];
      bf16x8 b1 = *(const bf16x8*)&Vt_lds[nt * 16 + li][32 + g * 8];
      acc[nt] = mfma16(a0, b0, acc[nt]);
      acc[nt] = mfma16(a1, b1, acc[nt]);
    }
  }

  float linv[4];
#pragma unroll
  for (int r = 0; r < 4; ++r)
    linv[r] = 1.0f / fmaxf(__shfl(acc[4][r], lane & 48), 1e-35f);

#pragma unroll
  for (int nt = 0; nt < 4; ++nt)
#pragma unroll
    for (int r = 0; r < 4; ++r) {
      int t = qt * 64 + mw + g * 4 + r;
      att[((size_t)b * T_SEQ + t) * CDIM + h * 64 + nt * 16 + li] =
          __float2bfloat16(acc[nt][r] * linv[r]);
    }
}

// ---------------- launch ----------------
extern "C" void kernel_launch(void* const* d_in, const int* in_sizes, int n_in,
                              void* d_out, int out_size, void* d_ws, size_t ws_size,
                              hipStream_t stream) {
  const float* x  = (const float*)d_in[0];
  const float* wq = (const float*)d_in[1];
  const float* wk = (const float*)d_in[2];
  const float* wv = (const float*)d_in[3];
  const float* wo = (const float*)d_in[4];
  const float* hd = (const float*)d_in[5];
  const float* sc = (const float*)d_in[6];
  float* out = (float*)d_out;

  // workspace layout (bytes), ~29.7 MB total
  char* ws = (char*)d_ws;
  bf16_t* wqkT = (bf16_t*)(ws + 0);          // 96*1024*2      = 196608
  bf16_t* wvT  = (bf16_t*)(ws + 196608);     // 1024*1024*2    = 2097152
  bf16_t* woT  = (bf16_t*)(ws + 2293760);    // 1024*1024*2
  float*  Qt   = (float*)(ws + 4390912);     // 3*32*2048*4    = 786432
  float*  Kt   = (float*)(ws + 5177344);     // 786432
  bf16_t* VT   = (bf16_t*)(ws + 5963776);    // 32*64*2048*2   = 8388608
  bf16_t* att  = (bf16_t*)(ws + 14352384);   // 4096*1024*2    = 8388608
  bf16_t* xb   = (bf16_t*)(ws + 22740992);   // 4096*1024*2    = 8388608

  k_cast<<<4096, 256, 0, stream>>>((const float4*)x, (ushort4*)xb, 1048576);

  k_transpose<<<dim3(2, 32), 256, 0, stream>>>(wq, wqkT, 1024, 48);
  k_transpose<<<dim3(2, 32), 256, 0, stream>>>(wk, wqkT + 48 * 1024, 1024, 48);
  k_transpose<<<dim3(32, 32), 256, 0, stream>>>(wv, wvT, 1024, 1024);
  k_transpose<<<dim3(32, 32), 256, 0, stream>>>(wo, woT, 1024, 1024);

  k_qkproj<<<256, 64, 0, stream>>>(xb, wqkT, hd, sc, Qt, Kt);

  // VT[vdim][b,t] = sum_k wvT[vdim][k] * xb[b,t][k]
  k_gemm_bt<<<dim3(32, 8), 256, 0, stream>>>(wvT, xb, VT, 1024, 4096, 1024, 0);

  k_attn<<<1024, 256, 0, stream>>>(Qt, Kt, VT, att);

  // out = att @ wo (fp32 out)
  k_gemm_bt<<<dim3(8, 32), 256, 0, stream>>>(att, woT, out, 4096, 1024, 1024, 1);
}